// Round 1
// baseline (225.426 us; speedup 1.0000x reference)
//
#include <hip/hip_runtime.h>

typedef short short8 __attribute__((ext_vector_type(8)));
typedef float floatx4 __attribute__((ext_vector_type(4)));

#define HWSZ 16384   // 128*128
#define WD 128
#define HD 128
#define CD 64
#define OD 64
#define TSTR 72      // bf16 LDS row stride: 144 B, 16B-aligned, 2-way banks (free)
#define OSTR 132     // fp32 epilogue stride: 16B-aligned, conflict-free
#define L2E2 2.8853900817779268f   // 2*log2(e)

__device__ __forceinline__ short f2bf(float f) {
    unsigned u = __builtin_bit_cast(unsigned, f);
    u += 0x7FFFu + ((u >> 16) & 1u);     // RNE
    return (short)(u >> 16);
}

__global__ __launch_bounds__(256, 4)
void paka_kernel(const float* __restrict__ x, const float* __restrict__ gc,
                 const float* __restrict__ gs, const float* __restrict__ wgt,
                 float* __restrict__ out)
{
    __shared__ union {
        struct { short t[128 * TSTR]; short w[64 * TSTR]; } s;
        float o[64 * OSTR];
    } lds;

    const int tid  = threadIdx.x;
    const int wave = tid >> 6;
    const int lane = tid & 63;
    const int b = blockIdx.x >> 7;      // 8 batches
    const int h = blockIdx.x & 127;     // 128 rows

    const float* xb  = x  + (size_t)b * CD * HWSZ;
    const float* gcb = gc + (size_t)b * CD * HWSZ;
    const float* gsb = gs + (size_t)b * 9 * HWSZ;

    // phase-1 thread mapping: oct -> 8 consecutive c, p0 -> pixel (w)
    const int oct = tid & 7;
    const int p0  = tid >> 3;           // 0..31, +32*pi
    const int c0  = oct * 8;

    // Hoist: 1+tanh(gc+gs) = 2 - 2/(1+exp2(L2E2*gc)*exp2(L2E2*gs)).
    // eg depends only on (c,p) -> compute once, reuse across all 9 taps.
    float eg[4][8];
    #pragma unroll
    for (int pi = 0; pi < 4; ++pi) {
        int p = p0 + 32 * pi;
        const float* gp = gcb + (size_t)c0 * HWSZ + h * WD + p;
        #pragma unroll
        for (int j = 0; j < 8; ++j)
            eg[pi][j] = __builtin_amdgcn_exp2f(gp[(size_t)j * HWSZ] * L2E2);
    }

    floatx4 acc[2][4];
    #pragma unroll
    for (int i = 0; i < 2; ++i)
        #pragma unroll
        for (int n = 0; n < 4; ++n)
            acc[i][n] = (floatx4){0.f, 0.f, 0.f, 0.f};

    const int row = lane & 15;
    const int q   = lane >> 4;
    const int mt0 = wave * 2;

    for (int k = 0; k < 9; ++k) {
        const int dh = k / 3 - 1, dw = k % 3 - 1;
        const int hh = h + dh;
        const bool rowok = (unsigned)hh < (unsigned)HD;

        __syncthreads();   // previous MFMA phase done reading LDS

        // stage W[:, :, k] -> lds.s.w[o][c] bf16 (16 KB fp32 src, L2-resident)
        #pragma unroll
        for (int it = 0; it < 16; ++it) {
            int idx = it * 256 + tid;
            int o = idx >> 6, c = idx & 63;
            lds.s.w[o * TSTR + c] = f2bf(wgt[o * 576 + c * 9 + k]);
        }

        // stage t chunk: t[p][c] = x[c][hh][p+dw] * filt
        #pragma unroll
        for (int pi = 0; pi < 4; ++pi) {
            int p = p0 + 32 * pi;
            int ww = p + dw;
            bool ok = rowok && ((unsigned)ww < (unsigned)WD);
            float es = __builtin_amdgcn_exp2f(gsb[k * HWSZ + h * WD + p] * L2E2);
            const float* xrow = xb + (size_t)c0 * HWSZ + hh * WD + ww;
            short8 tv;
            #pragma unroll
            for (int j = 0; j < 8; ++j) {
                float xv = ok ? xrow[(size_t)j * HWSZ] : 0.0f;
                float u = eg[pi][j] * es;                       // exp2(2log2e*(gc+gs))
                float filt = 2.0f - 2.0f * __builtin_amdgcn_rcpf(1.0f + u);
                tv[j] = f2bf(xv * filt);
            }
            *(short8*)&lds.s.t[p * TSTR + c0] = tv;             // ds_write_b128
        }

        __syncthreads();

        // MFMA: out[p][o] += t[p][c] * W[o][c]; wave owns 2 m-tiles x 4 n-tiles
        #pragma unroll
        for (int ks = 0; ks < 2; ++ks) {
            int kb = ks * 32 + q * 8;
            short8 a0 = *(const short8*)&lds.s.t[(mt0 * 16 + row) * TSTR + kb];
            short8 a1 = *(const short8*)&lds.s.t[((mt0 + 1) * 16 + row) * TSTR + kb];
            #pragma unroll
            for (int nt = 0; nt < 4; ++nt) {
                short8 bv = *(const short8*)&lds.s.w[(nt * 16 + row) * TSTR + kb];
                acc[0][nt] = __builtin_amdgcn_mfma_f32_16x16x32_bf16(a0, bv, acc[0][nt], 0, 0, 0);
                acc[1][nt] = __builtin_amdgcn_mfma_f32_16x16x32_bf16(a1, bv, acc[1][nt], 0, 0, 0);
            }
        }
    }

    __syncthreads();

    // D layout: col(=o) = lane&15, rowD(=p) = (lane>>4)*4 + reg. Transpose via LDS.
    #pragma unroll
    for (int i = 0; i < 2; ++i) {
        int prow = (mt0 + i) * 16 + q * 4;
        #pragma unroll
        for (int nt = 0; nt < 4; ++nt) {
            int o = nt * 16 + row;
            #pragma unroll
            for (int r = 0; r < 4; ++r)
                lds.o[o * OSTR + prow + r] = acc[i][nt][r];
        }
    }

    __syncthreads();

    // coalesced float4 stores: out[b][o][h][0..127]
    float* outb = out + ((size_t)b * OD) * HWSZ + h * WD;
    #pragma unroll
    for (int it = 0; it < 8; ++it) {
        int idx = it * 256 + tid;              // 2048 float4s
        int o = idx >> 5, p4 = (idx & 31) * 4;
        *(floatx4*)&outb[(size_t)o * HWSZ + p4] = *(const floatx4*)&lds.o[o * OSTR + p4];
    }
}

extern "C" void kernel_launch(void* const* d_in, const int* in_sizes, int n_in,
                              void* d_out, int out_size, void* d_ws, size_t ws_size,
                              hipStream_t stream) {
    const float* x   = (const float*)d_in[0];
    const float* gcp = (const float*)d_in[1];
    const float* gsp = (const float*)d_in[2];
    const float* wgt = (const float*)d_in[3];
    float* out = (float*)d_out;
    paka_kernel<<<dim3(1024), dim3(256), 0, stream>>>(x, gcp, gsp, wgt, out);
}

// Round 3
// 145.865 us; speedup vs baseline: 1.5454x; 1.5454x over previous
//
#include <hip/hip_runtime.h>
#include <hip/hip_bf16.h>

typedef short short8 __attribute__((ext_vector_type(8)));
typedef float floatx4 __attribute__((ext_vector_type(4)));

#define HWSZ 16384   // 128*128
#define WD 128
#define CD 64
#define OD 64
#define XSTR 72      // bf16 LDS row stride (144B): 16B-aligned, worst 2-way banks
#define OSTR 132     // fp32 epilogue stride
#define L2E2 2.8853900817779268f   // 2*log2(e)

__device__ __forceinline__ short f2bf(float f) {
    unsigned u = __builtin_bit_cast(unsigned, f);
    u += 0x7FFFu + ((u >> 16) & 1u);     // RNE
    return (short)(u >> 16);
}

// pack two floats -> packed bf16x2 (RNE; compiler should emit v_cvt_pk_bf16_f32)
__device__ __forceinline__ unsigned pack2bf(float a, float b) {
    __hip_bfloat162 h = __float22bfloat162_rn(float2{a, b});
    unsigned u;
    __builtin_memcpy(&u, &h, 4);
    return u;
}

__device__ __forceinline__ float bf2f(short s) {
    return __builtin_bit_cast(float, ((unsigned)(unsigned short)s) << 16);
}

// one-time repack: wgt[o][c][k] fp32 -> wp[k][o][c] bf16 (coalesced writes)
__global__ void prepack_w(const float* __restrict__ wgt, unsigned short* __restrict__ wp) {
    int idx = blockIdx.x * 256 + threadIdx.x;     // 9*64*64 = 36864
    if (idx < 9 * 64 * 64) {
        int k = idx >> 12, o = (idx >> 6) & 63, c = idx & 63;
        wp[idx] = (unsigned short)f2bf(wgt[o * 576 + c * 9 + k]);
    }
}

__global__ __launch_bounds__(256, 3)
void paka_kernel(const float* __restrict__ x, const float* __restrict__ gc,
                 const float* __restrict__ gs, const float* __restrict__ wgt,
                 const unsigned short* __restrict__ wp, float* __restrict__ out)
{
    __shared__ union {
        struct {
            short xl[130 * XSTR];     // raw x (bf16), slot = w+1, slots 0/129 = zero pad
            short wl[3][64 * XSTR];   // W bf16 for the 3 dw-taps of current dh
        } s;
        float o[64 * OSTR];           // epilogue transpose buffer
    } lds;

    const int tid  = threadIdx.x;
    const int wave = tid >> 6;
    const int lane = tid & 63;
    const int b = blockIdx.x >> 7;      // 8 batches
    const int h = blockIdx.x & 127;     // 128 rows

    const float* xb  = x  + (size_t)b * CD * HWSZ;
    const float* gcb = gc + (size_t)b * CD * HWSZ;
    const float* gsb = gs + (size_t)b * 9 * HWSZ;

    const int row = lane & 15;
    const int q   = lane >> 4;
    const int mt0 = wave * 2;

    // ---- prefetch eg = exp2(2log2e * gc[c][h][p]) for this lane's MFMA elements
    // (c,p) per lane: p = (mt0+mt)*16+row (quarter-wave-coalesced across lanes),
    // c = ks*32 + q*8 + j. 32 loads, 64B-granular coalescing, read once per block.
    float eg[2][2][8];
    #pragma unroll
    for (int mt = 0; mt < 2; ++mt) {
        int p = (mt0 + mt) * 16 + row;
        #pragma unroll
        for (int ks = 0; ks < 2; ++ks)
            #pragma unroll
            for (int j = 0; j < 8; ++j) {
                int c = ks * 32 + q * 8 + j;
                eg[mt][ks][j] = __builtin_amdgcn_exp2f(gcb[(size_t)c * HWSZ + h * WD + p] * L2E2);
            }
    }
    // ---- prefetch esv = exp2(2log2e * gs[k][h][p]) for all 9 taps
    float esv[9][2];
    #pragma unroll
    for (int k = 0; k < 9; ++k)
        #pragma unroll
        for (int mt = 0; mt < 2; ++mt) {
            int p = (mt0 + mt) * 16 + row;
            esv[k][mt] = __builtin_amdgcn_exp2f(gsb[k * HWSZ + h * WD + p] * L2E2);
        }

    // zero the two pad rows of xl (w = -1 and w = 128) once
    if (tid < 32)
        *(unsigned*)&lds.s.xl[0 * XSTR + tid * 2] = 0u;
    else if (tid < 64)
        *(unsigned*)&lds.s.xl[129 * XSTR + (tid - 32) * 2] = 0u;

    floatx4 acc[2][4];
    #pragma unroll
    for (int i = 0; i < 2; ++i)
        #pragma unroll
        for (int n = 0; n < 4; ++n)
            acc[i][n] = (floatx4){0.f, 0.f, 0.f, 0.f};

    #pragma unroll
    for (int dh = 0; dh < 3; ++dh) {
        const int hh = h + dh - 1;
        if ((unsigned)hh >= 128u) continue;   // block-uniform: taps contribute zero

        __syncthreads();   // previous MFMA phase done reading xl/wl

        // ---- stage W for the 3 dw-taps of this dh
        if (wp) {
            // packed bf16 [k][o][c]: contiguous 16B chunks, coalesced
            #pragma unroll
            for (int it = 0; it < 6; ++it) {
                int idx = it * 256 + tid;            // 0..1535
                int dw = idx >> 9, o = (idx >> 3) & 63, cg = idx & 7;
                short8 v = *(const short8*)&wp[(dh * 3 + dw) * 4096 + o * 64 + cg * 8];
                *(short8*)&lds.s.wl[dw][o * XSTR + cg * 8] = v;
            }
        } else {
            #pragma unroll
            for (int it = 0; it < 48; ++it) {
                int idx = it * 256 + tid;            // 0..12287
                int dw = idx >> 12, o = (idx >> 6) & 63, c = idx & 63;
                lds.s.wl[dw][o * XSTR + c] = f2bf(wgt[o * 576 + c * 9 + dh * 3 + dw]);
            }
        }

        // ---- stage x row hh: coalesced float4 along w, transpose via ushort2 LDS writes
        #pragma unroll
        for (int it = 0; it < 4; ++it) {
            int idx = it * 256 + tid;                // 0..1023
            int cp = idx >> 5;                       // c-pair 0..31
            int p4 = (idx & 31) * 4;
            const float* x0 = xb + (size_t)(2 * cp) * HWSZ + hh * WD + p4;
            floatx4 a = *(const floatx4*)x0;
            floatx4 c4 = *(const floatx4*)(x0 + HWSZ);
            #pragma unroll
            for (int i = 0; i < 4; ++i)
                *(unsigned*)&lds.s.xl[(p4 + i + 1) * XSTR + 2 * cp] = pack2bf(a[i], c4[i]);
        }

        __syncthreads();

        // ---- 3 taps share this staging: no syncs between dw phases
        #pragma unroll
        for (int dw = 0; dw < 3; ++dw) {
            const int k = dh * 3 + dw;
            #pragma unroll
            for (int ks = 0; ks < 2; ++ks) {
                short8 af[2];
                #pragma unroll
                for (int mt = 0; mt < 2; ++mt) {
                    int wslot = (mt0 + mt) * 16 + row + dw;   // = p + dw, xl slot of w=p+dw-1
                    short8 raw = *(const short8*)&lds.s.xl[wslot * XSTR + ks * 32 + q * 8];
                    float es = esv[k][mt];
                    #pragma unroll
                    for (int jj = 0; jj < 4; ++jj) {
                        float d0 = fmaf(eg[mt][ks][2 * jj],     es, 1.0f);
                        float d1 = fmaf(eg[mt][ks][2 * jj + 1], es, 1.0f);
                        float r0 = __builtin_amdgcn_rcpf(d0);
                        float r1 = __builtin_amdgcn_rcpf(d1);
                        float x20 = bf2f(raw[2 * jj]);     x20 += x20;
                        float x21 = bf2f(raw[2 * jj + 1]); x21 += x21;
                        float t0 = fmaf(-x20, r0, x20);    // x * (2 - 2/(1+u))
                        float t1 = fmaf(-x21, r1, x21);
                        ((unsigned*)&af[mt])[jj] = pack2bf(t0, t1);
                    }
                }
                #pragma unroll
                for (int nt = 0; nt < 4; ++nt) {
                    short8 bv = *(const short8*)&lds.s.wl[dw][(nt * 16 + row) * XSTR + ks * 32 + q * 8];
                    acc[0][nt] = __builtin_amdgcn_mfma_f32_16x16x32_bf16(af[0], bv, acc[0][nt], 0, 0, 0);
                    acc[1][nt] = __builtin_amdgcn_mfma_f32_16x16x32_bf16(af[1], bv, acc[1][nt], 0, 0, 0);
                }
            }
        }
    }

    __syncthreads();

    // D layout: col(=o) = lane&15, rowD(=p) = (lane>>4)*4 + reg. Transpose via LDS.
    #pragma unroll
    for (int i = 0; i < 2; ++i) {
        int prow = (mt0 + i) * 16 + q * 4;
        #pragma unroll
        for (int nt = 0; nt < 4; ++nt) {
            int o = nt * 16 + row;
            #pragma unroll
            for (int r = 0; r < 4; ++r)
                lds.o[o * OSTR + prow + r] = acc[i][nt][r];
        }
    }

    __syncthreads();

    // coalesced float4 stores: out[b][o][h][0..127]
    float* outb = out + ((size_t)b * OD) * HWSZ + h * WD;
    #pragma unroll
    for (int it = 0; it < 8; ++it) {
        int idx = it * 256 + tid;              // 2048 float4s
        int o = idx >> 5, p4 = (idx & 31) * 4;
        *(floatx4*)&outb[(size_t)o * HWSZ + p4] = *(const floatx4*)&lds.o[o * OSTR + p4];
    }
}

extern "C" void kernel_launch(void* const* d_in, const int* in_sizes, int n_in,
                              void* d_out, int out_size, void* d_ws, size_t ws_size,
                              hipStream_t stream) {
    const float* x   = (const float*)d_in[0];
    const float* gcp = (const float*)d_in[1];
    const float* gsp = (const float*)d_in[2];
    const float* wgt = (const float*)d_in[3];
    float* out = (float*)d_out;

    const bool use_wp = ws_size >= (size_t)(9 * 64 * 64 * sizeof(unsigned short));
    unsigned short* wp = use_wp ? (unsigned short*)d_ws : nullptr;
    if (use_wp)
        prepack_w<<<dim3(144), dim3(256), 0, stream>>>(wgt, wp);
    paka_kernel<<<dim3(1024), dim3(256), 0, stream>>>(x, gcp, gsp, wgt, wp, out);
}